// Round 2
// baseline (114.824 us; speedup 1.0000x reference)
//
#include <hip/hip_runtime.h>
#include <hip/hip_fp16.h>

// DFMB PSROIAlign — separable (rank-1) weights + phase-split sides + fp16
// row-line gather source.
//
// R7/R9 lesson: cost is pinned by DISTINCT 64B L1-LINES fetched per bin, not
// gather-instruction count (R9 cut instr 18->12 for only -6%; fitted model
// line_cost ~ 4x instr_cost). Working set >> 32KB L1 => every patch line is an
// L1 miss filled from L2; 64 lanes/wave touch 64 distinct planes.
//
// R10: make each patch ROW exactly ONE line. A row = 3 consecutive pixels x
// 10ch x fp16 = 60B <= 64B. Store ftR as THREE phase-shifted copies of 64B
// row-lines: copy m, line g holds pixels [3g+m, 3g+m+2], layout
// [pix0: ch0-9 (5dw)][pix1: 5dw][pix2: 5dw][pad dw]. For window start fp:
// m = fp%3, g = fp/3 -> whole row in one line (4 x b128, 3 are L1 hits).
// Column clamp (X0+q>33) is merged into per-element weights ew[] (linearity:
// sum_q w_q * v[clamp(col_q)] == sum_j (sum of w over clamped q==j) * v[j]).
// Lines/bin: ~7.5 -> 3. ws: 3 x 18882 x 64B = 3.46 MB (fits 4MB L2/XCD).
// NaN safety (ws is poisoned each iter): prep rewrites every readable slot,
// incl. zeroed tail pixels NPIX..NPIX+1; ew=0 elements multiply finite data.

#define NC 10
#define NBIN 49
#define FH 34
#define FW 34
#define PLANE (FH * FW)
#define NPIX (NBIN * PLANE)  // 56644
#define GPC 18882            // lines per phase copy: covers pixels up to 3*18881+m+2
#define RPB 16               // rois per block
#define TSTRIDE 491          // out-tile row stride (odd -> conflict-free flush)
#define NSIDE 14

__global__ __launch_bounds__(256) void prep_kernel(
    const float* __restrict__ ft, unsigned int* __restrict__ ftR)
{
    const int p = blockIdx.x * 256 + threadIdx.x;  // over NPIX+2 (2 zero tail pixels)
    if (p >= NPIX + 2) return;
    unsigned int h2[5];
    if (p < NPIX) {
#pragma unroll
        for (int c = 0; c < 5; ++c) {
            const __half lo = __float2half_rn(ft[(2 * c)     * NPIX + p]);
            const __half hi = __float2half_rn(ft[(2 * c + 1) * NPIX + p]);
            const __half2 hh = __halves2half2(lo, hi);
            h2[c] = *(const unsigned int*)&hh;
        }
    } else {
#pragma unroll
        for (int c = 0; c < 5; ++c) h2[c] = 0u;  // tail: finite zeros
    }
    // pixel p lives in copy m (m<=p) at line g=(p-m)/3, slot j=(p-m)%3
#pragma unroll
    for (int m = 0; m < 3; ++m) {
        if (p >= m) {
            const int t = p - m;
            const int g = t / 3;
            const int j = t - 3 * g;
            if (g < GPC) {
                unsigned int* d = ftR + ((size_t)m * GPC + g) * 16 + j * 5;
#pragma unroll
                for (int c = 0; c < 5; ++c) d[c] = h2[c];
            }
        }
    }
}

__device__ __forceinline__ void fma2(float w, unsigned int u, float& s0, float& s1)
{
    const __half2 h = *(const __half2*)&u;
    s0 = fmaf(w, __half2float(__low2half(h)),  s0);   // -> v_fma_mix_f32
    s1 = fmaf(w, __half2float(__high2half(h)), s1);
}

__global__ __launch_bounds__(256, 4) void main_kernel(
    const float* __restrict__ rois, const unsigned int* __restrict__ ftR,
    const float* __restrict__ ft, float* __restrict__ out, int N, int use_t)
{
    __shared__ float sides[NSIDE][RPB][8];  // 7 KB
    __shared__ float tile[RPB][TSTRIDE];    // 31.4 KB

    const int r = threadIdx.x & (RPB - 1);  // roi within block
    const int s = threadIdx.x >> 4;         // slot 0..15
    const int n = blockIdx.x * RPB + r;
    const bool valid = (n < N);

    float rsw = 0.f, rsh = 0.f, rew = 0.f, reh = 0.f;
    if (valid) {
        rsw = rois[n * 5 + 1] * 0.125f;  // /STRIDE(8), exact pow2
        rsh = rois[n * 5 + 2] * 0.125f;
        rew = rois[n * 5 + 3] * 0.125f;
        reh = rois[n * 5 + 4] * 0.125f;
    }
    // Explicit _rn chain: floor/ceil/compare inputs must bit-match numpy fp32.
    float rheight = __fsub_rn(reh, rsh);
    if (!(rheight > 0.1f)) rheight = 0.1f;
    float rwidth = __fsub_rn(rew, rsw);
    if (!(rwidth > 0.1f)) rwidth = 0.1f;
    const float bsh   = __fdiv_rn(rheight, 7.0f);
    const float bsw   = __fdiv_rn(rwidth, 7.0f);
    const float sub_h = __fdiv_rn(bsh, 4.0f);
    const float sub_w = __fdiv_rn(bsw, 4.0f);

    // ---- phase 1: one axis-side per slot (slots 0..13 active) ----
    if (s < NSIDE) {
        const bool isY = (s < 7);
        const int  k   = isY ? s : s - 7;
        const float st = isY ? rsh : rsw;
        const float bs = isY ? bsh : bsw;
        const float sb = isY ? sub_h : sub_w;
        const float start = floorf(__fadd_rn(st, __fmul_rn((float)k, bs)));

        float A[3] = {0.f, 0.f, 0.f}, B[3] = {0.f, 0.f, 0.f};
        float cnt = 0.f;
        int P0 = 0;
#pragma unroll
        for (int i = 0; i < 4; ++i) {
            const float h = __fadd_rn(start, __fmul_rn((float)i + 0.5f, sb));
            const bool ok = (h > -1.0f) && (h < 34.0f);
            const int p1 = (int)floorf(h);
            const int p2 = (int)ceilf(h);
            const bool v1 = (p1 >= 0) && (p1 < 34);
            const bool v2 = (p2 >= 0) && (p2 < 34);
            const int p1c = min(max(p1, 0), 33);
            const int p2c = min(max(p2, 0), 33);
            const float d = __fsub_rn(h, (float)p1c);  // vs CLIPPED corner
            if (i == 0) P0 = p1c;                      // min (h increasing)
            const int i1 = p1c - P0, i2 = p2c - P0;    // in {0,1,2}
            const float t1 = ok ? (1.0f - d) : 0.0f;
            const float t2 = ok ? d : 0.0f;
            // bad11 = (!x1v || !x2v) && (y1v || y2v): X carries "invalid",
            // Y carries "valid".
            const bool bsel = isY ? (v1 || v2) : ((!v1) || (!v2));
            const float tb = (ok && bsel) ? (1.0f - d) : 0.0f;
            cnt += ok ? 1.0f : 0.0f;
#pragma unroll
            for (int p = 0; p < 3; ++p) {
                A[p] += (i1 == p) ? t1 : 0.0f;
                A[p] += (i2 == p) ? t2 : 0.0f;
                B[p] += (i1 == p) ? tb : 0.0f;
            }
        }
        float* sp = &sides[s][r][0];
        sp[0] = A[0]; sp[1] = A[1]; sp[2] = A[2];
        sp[3] = B[0]; sp[4] = B[1]; sp[5] = B[2];
        sp[6] = cnt;  sp[7] = (float)P0;
    }
    __syncthreads();

    // ---- phase 2: 4 bins/thread; 3 row-lines per bin (12 b128, 3 L1 lines) ----
#pragma unroll
    for (int j = 0; j < 4; ++j) {
        const int bin = j * RPB + s;
        if (valid && bin < NBIN) {
            const int ph = bin / 7;
            const int pw = bin - ph * 7;

            const float4 ya = *(const float4*)&sides[ph][r][0];
            const float4 yb = *(const float4*)&sides[ph][r][4];
            const float4 xa = *(const float4*)&sides[7 + pw][r][0];
            const float4 xb = *(const float4*)&sides[7 + pw][r][4];
            const float AY[3] = {ya.x, ya.y, ya.z};
            const float BY[3] = {ya.w, yb.x, yb.y};
            const float cntY  = yb.z;
            const int   Y0    = (int)yb.w;
            const float AX[3] = {xa.x, xa.y, xa.z};
            const float BX[3] = {xa.w, xb.x, xb.y};
            const float cntX  = xb.z;
            const int   X0    = (int)xb.w;

            const int binbase = bin * PLANE;
            const int rowo[3] = {binbase + Y0 * FW,
                                 binbase + min(Y0 + 1, FH - 1) * FW,
                                 binbase + min(Y0 + 2, FH - 1) * FW};

            float wgt[9];
#pragma unroll
            for (int p = 0; p < 3; ++p)
#pragma unroll
                for (int q = 0; q < 3; ++q)
                    wgt[3 * p + q] = AY[p] * AX[q] - BY[p] * BX[q];

            float sum[NC];
#pragma unroll
            for (int c = 0; c < NC; ++c) sum[c] = 0.f;

            if (use_t) {
                const int e = (FW - 1) - X0;  // >= 0; clamp width of row window
                unsigned int rv[3][15];
                float ew[3][3];
#pragma unroll
                for (int p = 0; p < 3; ++p) {
                    const float w0 = wgt[3 * p], w1 = wgt[3 * p + 1], w2 = wgt[3 * p + 2];
                    // merge clamped-column weights onto the clamped element
                    const float s12 = w1 + w2;
                    ew[p][0] = (e < 1) ? (w0 + s12) : w0;
                    ew[p][1] = (e < 1) ? 0.f : ((e < 2) ? s12 : w1);
                    ew[p][2] = (e < 2) ? 0.f : w2;
                    // zero-weight row -> shared dummy line at plane origin
                    const bool rnz = (w0 != 0.0f) || (w1 != 0.0f) || (w2 != 0.0f);
                    const int fp = rnz ? (rowo[p] + X0) : binbase;
                    const int g = fp / 3;       // magic-mul div
                    const int m = fp - 3 * g;
                    const unsigned int* lp = ftR + ((size_t)m * GPC + g) * 16;
                    const uint4 a = *(const uint4*)lp;
                    const uint4 b = *(const uint4*)(lp + 4);
                    const uint4 c4 = *(const uint4*)(lp + 8);
                    const uint4 d4 = *(const uint4*)(lp + 12);
                    rv[p][0]  = a.x;  rv[p][1]  = a.y;  rv[p][2]  = a.z;  rv[p][3]  = a.w;
                    rv[p][4]  = b.x;  rv[p][5]  = b.y;  rv[p][6]  = b.z;  rv[p][7]  = b.w;
                    rv[p][8]  = c4.x; rv[p][9]  = c4.y; rv[p][10] = c4.z; rv[p][11] = c4.w;
                    rv[p][12] = d4.x; rv[p][13] = d4.y; rv[p][14] = d4.z;  // d4.w = pad
                }
#pragma unroll
                for (int p = 0; p < 3; ++p)
#pragma unroll
                    for (int c = 0; c < 5; ++c) {
                        fma2(ew[p][0], rv[p][c],      sum[2 * c], sum[2 * c + 1]);
                        fma2(ew[p][1], rv[p][5 + c],  sum[2 * c], sum[2 * c + 1]);
                        fma2(ew[p][2], rv[p][10 + c], sum[2 * c], sum[2 * c + 1]);
                    }
            } else {
                const int colo[3] = {X0, min(X0 + 1, FW - 1), min(X0 + 2, FW - 1)};
                int off[9];
#pragma unroll
                for (int p = 0; p < 3; ++p)
#pragma unroll
                    for (int q = 0; q < 3; ++q)
                        off[3 * p + q] = (wgt[3 * p + q] != 0.0f) ? (rowo[p] + colo[q])
                                                                  : binbase;
#pragma unroll
                for (int k = 0; k < 9; ++k) {
                    const float w = wgt[k];
#pragma unroll
                    for (int c = 0; c < NC; ++c)
                        sum[c] = fmaf(w, ft[c * NPIX + off[k]], sum[c]);
                }
            }

            const float cnt = cntY * cntX;
            const float inv = (cnt > 0.0f) ? __fdiv_rn(1.0f, cnt) : 1.0f;
            float* tp = &tile[r][0];
#pragma unroll
            for (int c = 0; c < NC; ++c) tp[c * NBIN + bin] = sum[c] * inv;
        }
    }

    __syncthreads();

    // Coalesced flush: 16 rois x 490 contiguous floats each.
    const int n0 = blockIdx.x * RPB;
    for (int i = threadIdx.x; i < RPB * (NC * NBIN); i += 256) {
        const int row = i / (NC * NBIN);
        const int col = i - row * (NC * NBIN);
        const int n2 = n0 + row;
        if (n2 < N) out[(size_t)n2 * (NC * NBIN) + col] = tile[row][col];
    }
}

extern "C" void kernel_launch(void* const* d_in, const int* in_sizes, int n_in,
                              void* d_out, int out_size, void* d_ws, size_t ws_size,
                              hipStream_t stream) {
    const float* ft   = (const float*)d_in[0];
    const float* rois = (const float*)d_in[1];
    float* out        = (float*)d_out;
    const int N = in_sizes[1] / 5;

    // 3 phase copies x GPC lines x 64B = 3,625,344 B
    const size_t need = (size_t)3 * GPC * 64;
    const int use_t = (ws_size >= need) ? 1 : 0;
    unsigned int* ftR = (unsigned int*)d_ws;

    if (use_t) {
        prep_kernel<<<(NPIX + 2 + 255) / 256, 256, 0, stream>>>(ft, ftR);
    }
    main_kernel<<<(N + RPB - 1) / RPB, 256, 0, stream>>>(rois, ftR, ft, out, N, use_t);
}